// Round 9
// baseline (855.655 us; speedup 1.0000x reference)
//
#include <hip/hip_runtime.h>
#include <hip/hip_fp16.h>

#define NBK 512      // dst-range buckets
#define CHUNK 2048   // edges per partition block
#define CAPN_MAX 208 // max nodes per bucket (LDS sizing); capN=196 for N=100000
// pack: code = (dl<<17)|src ; valid: N<2^17, capN<2^8... dl<208 fits 8 bits

// ---------------- x -> fp16 copy (gather payload compression) ----------------
__global__ void k_cvt(const float* __restrict__ x, __half* __restrict__ xh, int total) {
  int i = (blockIdx.x * 256 + threadIdx.x) * 8;
  if (i >= total) return;
  float4 a = *(const float4*)(x + i);
  float4 b = *(const float4*)(x + i + 4);
  __half2* dst = (__half2*)(xh + i);
  dst[0] = __floats2half2_rn(a.x, a.y);
  dst[1] = __floats2half2_rn(a.z, a.w);
  dst[2] = __floats2half2_rn(b.x, b.y);
  dst[3] = __floats2half2_rn(b.z, b.w);
}

// ---------------- partition edges into dst-range buckets --------------------------
// bucket b = d / capN via magic multiply: M = ceil(2^34/capN), exact for d < 2^17.
__launch_bounds__(256)
__global__ void k_part(const int* __restrict__ srcI, const int* __restrict__ dstI,
                       int* __restrict__ gcur, int* __restrict__ pairs,
                       int E, int N, int capN, int capE, unsigned long long M) {
  __shared__ int hist[NBK];
  __shared__ int base[NBK];
  __shared__ int cnt[NBK];
  int tid = threadIdx.x;  // 256
  int e0 = blockIdx.x * CHUNK;
  int eend = min(e0 + CHUNK, E);
  for (int i = tid; i < NBK; i += 256) hist[i] = 0;
  __syncthreads();
  int dc[8], bc[8];                 // static-indexed caches (full unroll -> regs)
#pragma unroll
  for (int j = 0; j < 8; ++j) {
    int e = e0 + tid + j * 256;
    int d = -1;
    if (e < eend) {
      int dd = dstI[e];
      if ((unsigned)dd < (unsigned)N) d = dd;
    }
    int b = -1;
    if (d >= 0) {
      b = (int)(((unsigned long long)(unsigned)d * M) >> 34);
      atomicAdd(&hist[b], 1);
    }
    dc[j] = d; bc[j] = b;
  }
  __syncthreads();
  for (int i = tid; i < NBK; i += 256) {
    base[i] = i * capE + atomicAdd(&gcur[i], hist[i]);
    cnt[i] = 0;
  }
  __syncthreads();
#pragma unroll
  for (int j = 0; j < 8; ++j) {
    if (dc[j] >= 0) {
      int e = e0 + tid + j * 256;
      int s = srcI[e];
      if ((unsigned)s < (unsigned)N) {
        int b = bc[j];
        int slot = base[b] + atomicAdd(&cnt[b], 1);
        if (slot < (b + 1) * capE)
          pairs[slot] = ((dc[j] - b * capN) << 17) | s;
      }
    }
  }
}

// ---------------- fused bucket aggregation, 64-dim: m = mean_agg(xh), deg --------
// one block (512 thr = 8 waves) per bucket; LDS fp32 accumulators + counts.
__launch_bounds__(512)
__global__ void k_aggm(const __half* __restrict__ xh, const int* __restrict__ pairs,
                       const int* __restrict__ gcur, float* __restrict__ m,
                       int* __restrict__ deg, int n, int capN, int capE) {
  __shared__ float acc[CAPN_MAX * 64];   // 53 KB
  __shared__ int cntL[CAPN_MAX];
  int q = blockIdx.x;
  int tid = threadIdx.x;
  int qbase = q * capN;
  int nloc = min(n - qbase, capN);
  if (nloc <= 0) return;
  int base = q * capE;
  int ecnt = min(gcur[q], capE);
  for (int i = tid; i < nloc * 64; i += 512) acc[i] = 0.f;
  for (int i = tid; i < nloc; i += 512) cntL[i] = 0;
  __syncthreads();
  int wid = tid >> 6, lane = tid & 63;
  for (int e0 = wid * 8; e0 < ecnt; e0 += 64) {
#pragma unroll
    for (int j = 0; j < 8; ++j) {
      int e = e0 + j;
      if (e < ecnt) {                       // wave-uniform predicate
        int code = pairs[base + e];
        int dl = (unsigned)code >> 17;
        int s = code & 0x1FFFF;
        float v = __half2float(xh[(size_t)s * 64 + lane]);
        atomicAdd(&acc[dl * 64 + lane], v); // ds_add_f32, 2 lanes/bank (free)
        if (lane == 0) atomicAdd(&cntL[dl], 1);
      }
    }
  }
  __syncthreads();
  for (int i = tid; i < nloc * 64; i += 512) {
    int r = i >> 6;
    int c = cntL[r];
    float inv = (c > 0) ? 1.f / (float)c : 0.f;
    m[(size_t)(qbase + r) * 64 + (i & 63)] = acc[i] * inv;
  }
  for (int i = tid; i < nloc; i += 512) deg[qbase + i] = cntL[i];
}

// ---------------- layer1 GEMM: h = relu([m|x] @ [W1l;W1r] + b1) -------------------
__launch_bounds__(256, 4)
__global__ void k_h(const float* __restrict__ m, const float* __restrict__ x,
                    const float* __restrict__ Wl, const float* __restrict__ Wr,
                    const float* __restrict__ b1, float* __restrict__ h, int n) {
  __shared__ float sAT[32 * 68];
  __shared__ float sW[32 * 64];
  int tid = threadIdx.x;
  int row0 = blockIdx.x * 64;
  int colT = tid & 15;
  int rowT = tid >> 4;
  float acc[4][4];
#pragma unroll
  for (int r = 0; r < 4; ++r)
#pragma unroll
    for (int c = 0; c < 4; ++c) acc[r][c] = 0.f;

  for (int kt = 0; kt < 4; ++kt) {
    const float* asrc = (kt < 2) ? m : x;
    const float* wsrc = (kt < 2) ? Wl : Wr;
    int ko = (kt & 1) * 32;
    __syncthreads();
    {
      int f = tid;
#pragma unroll
      for (int i = 0; i < 2; ++i, f += 256) {
        int r = f >> 3, kq = f & 7;
        int rr = row0 + r; if (rr > n - 1) rr = n - 1;
        float4 v = *(const float4*)(asrc + (size_t)rr * 64 + ko + kq * 4);
        sAT[(kq * 4 + 0) * 68 + r] = v.x;
        sAT[(kq * 4 + 1) * 68 + r] = v.y;
        sAT[(kq * 4 + 2) * 68 + r] = v.z;
        sAT[(kq * 4 + 3) * 68 + r] = v.w;
      }
      int g = tid;
#pragma unroll
      for (int i = 0; i < 2; ++i, g += 256) {
        int wr = g >> 4, cq = g & 15;
        float4 v = *(const float4*)(wsrc + (size_t)(ko + wr) * 64 + cq * 4);
        *(float4*)&sW[wr * 64 + cq * 4] = v;
      }
    }
    __syncthreads();
#pragma unroll 4
    for (int k = 0; k < 32; ++k) {
      float4 a = *(const float4*)&sAT[k * 68 + rowT * 4];
      float4 w = *(const float4*)&sW[k * 64 + colT * 4];
      acc[0][0] += a.x * w.x; acc[0][1] += a.x * w.y; acc[0][2] += a.x * w.z; acc[0][3] += a.x * w.w;
      acc[1][0] += a.y * w.x; acc[1][1] += a.y * w.y; acc[1][2] += a.y * w.z; acc[1][3] += a.y * w.w;
      acc[2][0] += a.z * w.x; acc[2][1] += a.z * w.y; acc[2][2] += a.z * w.z; acc[2][3] += a.z * w.w;
      acc[3][0] += a.w * w.x; acc[3][1] += a.w * w.y; acc[3][2] += a.w * w.z; acc[3][3] += a.w * w.w;
    }
  }
  float4 bb = *(const float4*)(b1 + colT * 4);
#pragma unroll
  for (int r = 0; r < 4; ++r) {
    int row = row0 + rowT * 4 + r;
    if (row < n) {
      float4 o;
      o.x = fmaxf(acc[r][0] + bb.x, 0.f);
      o.y = fmaxf(acc[r][1] + bb.y, 0.f);
      o.z = fmaxf(acc[r][2] + bb.z, 0.f);
      o.w = fmaxf(acc[r][3] + bb.w, 0.f);
      *(float4*)(h + (size_t)row * 64 + colT * 4) = o;
    }
  }
}

// ---------------- layer2 GEMM: p16 = half(h@W2l), q = h@W2r (to d_out) ------------
__launch_bounds__(256, 4)
__global__ void k_pq(const float* __restrict__ h, const float* __restrict__ W2l,
                     const float* __restrict__ W2r, __half* __restrict__ p16,
                     float* __restrict__ q, int n) {
  __shared__ float sAT[32 * 132];
  __shared__ float sW[32 * 32];
  int tid = threadIdx.x;
  int row0 = blockIdx.x * 128;
  int colT = tid & 7;
  int rowT = tid >> 3;
  float acc[4][4];
#pragma unroll
  for (int r = 0; r < 4; ++r)
#pragma unroll
    for (int c = 0; c < 4; ++c) acc[r][c] = 0.f;

  for (int kt = 0; kt < 2; ++kt) {
    int ko = kt * 32;
    __syncthreads();
    {
      int f = tid;
#pragma unroll
      for (int i = 0; i < 4; ++i, f += 256) {
        int r = f >> 3, kq = f & 7;
        int rr = row0 + r; if (rr > n - 1) rr = n - 1;
        float4 v = *(const float4*)(h + (size_t)rr * 64 + ko + kq * 4);
        sAT[(kq * 4 + 0) * 132 + r] = v.x;
        sAT[(kq * 4 + 1) * 132 + r] = v.y;
        sAT[(kq * 4 + 2) * 132 + r] = v.z;
        sAT[(kq * 4 + 3) * 132 + r] = v.w;
      }
      int wr = tid >> 3, cq = tid & 7;
      const float* wsrc = (cq < 4) ? W2l : W2r;
      int cc = (cq & 3) * 4;
      float4 v = *(const float4*)(wsrc + (size_t)(ko + wr) * 16 + cc);
      *(float4*)&sW[wr * 32 + cq * 4] = v;
    }
    __syncthreads();
#pragma unroll 4
    for (int k = 0; k < 32; ++k) {
      float4 a = *(const float4*)&sAT[k * 132 + rowT * 4];
      float4 w = *(const float4*)&sW[k * 32 + colT * 4];
      acc[0][0] += a.x * w.x; acc[0][1] += a.x * w.y; acc[0][2] += a.x * w.z; acc[0][3] += a.x * w.w;
      acc[1][0] += a.y * w.x; acc[1][1] += a.y * w.y; acc[1][2] += a.y * w.z; acc[1][3] += a.y * w.w;
      acc[2][0] += a.z * w.x; acc[2][1] += a.z * w.y; acc[2][2] += a.z * w.z; acc[2][3] += a.z * w.w;
      acc[3][0] += a.w * w.x; acc[3][1] += a.w * w.y; acc[3][2] += a.w * w.z; acc[3][3] += a.w * w.w;
    }
  }
#pragma unroll
  for (int r = 0; r < 4; ++r) {
    int row = row0 + rowT * 4 + r;
    if (row < n) {
      if (colT < 4) {
        __half2* dst = (__half2*)(p16 + (size_t)row * 16 + colT * 4);
        dst[0] = __floats2half2_rn(acc[r][0], acc[r][1]);
        dst[1] = __floats2half2_rn(acc[r][2], acc[r][3]);
      } else {
        *(float4*)(q + (size_t)row * 16 + (colT - 4) * 4) =
            make_float4(acc[r][0], acc[r][1], acc[r][2], acc[r][3]);
      }
    }
  }
}

// ---------------- fused bucket aggregation, 16-dim + epilogue ---------------------
// out = mean_agg(p16) + q + b2   (out already holds q from k_pq)
__launch_bounds__(256)
__global__ void k_aggq(const __half* __restrict__ p16, const int* __restrict__ pairs,
                       const int* __restrict__ gcur, const int* __restrict__ deg,
                       const float* __restrict__ b2, float* __restrict__ out,
                       int n, int capN, int capE) {
  __shared__ float acc[CAPN_MAX * 16];   // 13 KB
  int q = blockIdx.x;
  int tid = threadIdx.x;
  int qbase = q * capN;
  int nloc = min(n - qbase, capN);
  if (nloc <= 0) return;
  int base = q * capE;
  int ecnt = min(gcur[q], capE);
  for (int i = tid; i < nloc * 16; i += 256) acc[i] = 0.f;
  __syncthreads();
  int wid = tid >> 6, lane = tid & 63;
  int esub = lane >> 4, dim = lane & 15;   // 4 edges per wave-iter
  for (int e0 = wid * 16; e0 < ecnt; e0 += 64) {
#pragma unroll
    for (int j = 0; j < 4; ++j) {
      int e = e0 + j * 4 + esub;
      if (e < ecnt) {
        int code = pairs[base + e];
        int dl = (unsigned)code >> 17;
        int s = code & 0x1FFFF;
        float v = __half2float(p16[(size_t)s * 16 + dim]);
        atomicAdd(&acc[dl * 16 + dim], v);
      }
    }
  }
  __syncthreads();
  for (int i = tid; i < nloc * 16; i += 256) {
    int r = i >> 4, dd = i & 15;
    int dg = deg[qbase + r];
    float inv = (dg > 0) ? 1.f / (float)dg : 0.f;
    size_t o = (size_t)(qbase + r) * 16 + dd;
    out[o] = acc[i] * inv + out[o] + b2[dd];
  }
}

extern "C" void kernel_launch(void* const* d_in, const int* in_sizes, int n_in,
                              void* d_out, int out_size, void* d_ws, size_t ws_size,
                              hipStream_t stream) {
  const float* x   = (const float*)d_in[0];
  const int*   ei  = (const int*)d_in[1];
  const float* W1l = (const float*)d_in[2];
  const float* W1r = (const float*)d_in[3];
  const float* b1  = (const float*)d_in[4];
  const float* W2l = (const float*)d_in[5];
  const float* W2r = (const float*)d_in[6];
  const float* b2  = (const float*)d_in[7];
  float* out = (float*)d_out;

  int N = in_sizes[0] / 64;
  int E = in_sizes[1] / 2;
  const int* srcI = ei;
  const int* dstI = ei + E;

  int capN = (N + NBK - 1) / NBK;             // 196 for N=100000
  int capE = E / NBK + 512;                   // bucket capacity (~9 sigma slack)
  unsigned long long M = ((1ULL << 34) + capN - 1) / (unsigned long long)capN;

  size_t off = 0;
  auto alloc = [&](size_t bytes) -> char* {
    char* r = (char*)d_ws + off;
    off = (off + bytes + 255) & ~(size_t)255;
    return r;
  };
  int*    deg   = (int*)alloc((size_t)N * 4);
  int*    gcur  = (int*)alloc(NBK * 4);
  int*    pairs = (int*)alloc((size_t)NBK * capE * 4);
  __half* xh    = (__half*)alloc((size_t)N * 64 * 2);
  float*  m     = (float*)alloc((size_t)N * 64 * 4);
  float*  h     = (float*)alloc((size_t)N * 64 * 4);
  __half* p16   = (__half*)alloc((size_t)N * 16 * 2);
  if (off > ws_size) return;                  // visible failure if ws too small
  if (N > (1 << 17) || capN > CAPN_MAX) return;  // packing/LDS validity

  hipMemsetAsync(gcur, 0, NBK * 4, stream);
  k_cvt<<<(N * 64 + 2047) / 2048, 256, 0, stream>>>(x, xh, N * 64);
  k_part<<<(E + CHUNK - 1) / CHUNK, 256, 0, stream>>>(srcI, dstI, gcur, pairs, E, N, capN, capE, M);

  // layer 1: m = mean_agg(xh) (direct LDS aggregation); h = relu(m@W1l + x@W1r + b1)
  k_aggm<<<NBK, 512, 0, stream>>>(xh, pairs, gcur, m, deg, N, capN, capE);
  k_h<<<(N + 63) / 64, 256, 0, stream>>>(m, x, W1l, W1r, b1, h, N);

  // layer 2 (transform-first): p16 = h@W2l (fp16), q = h@W2r (to d_out)
  k_pq<<<(N + 127) / 128, 256, 0, stream>>>(h, W2l, W2r, p16, out, N);
  k_aggq<<<NBK, 256, 0, stream>>>(p16, pairs, gcur, deg, b2, out, N, capN, capE);
}

// Round 10
// 261.547 us; speedup vs baseline: 3.2715x; 3.2715x over previous
//
#include <hip/hip_runtime.h>
#include <hip/hip_fp16.h>

#define NB 256      // dst-range buckets
#define CHUNK 2048  // edges per partition block
// pack: code = (dl<<17)|src ; valid because N=100000<2^17 and capN=391<2^9

// ---------------- x -> fp16 copy (gather payload compression) ----------------
__global__ void k_cvt(const float* __restrict__ x, __half* __restrict__ xh, int total) {
  int i = (blockIdx.x * 256 + threadIdx.x) * 8;
  if (i >= total) return;
  float4 a = *(const float4*)(x + i);
  float4 b = *(const float4*)(x + i + 4);
  __half2* dst = (__half2*)(xh + i);
  dst[0] = __floats2half2_rn(a.x, a.y);
  dst[1] = __floats2half2_rn(a.z, a.w);
  dst[2] = __floats2half2_rn(b.x, b.y);
  dst[3] = __floats2half2_rn(b.z, b.w);
}

// ---------------- phase 1: partition edges into dst-range buckets ----------------
__launch_bounds__(256)
__global__ void k_part(const int* __restrict__ srcI, const int* __restrict__ dstI,
                       int* __restrict__ gcur, int* __restrict__ pairs,
                       int E, int N, int capN, int capE) {
  __shared__ int hist[NB];
  __shared__ int base[NB];
  __shared__ int cnt[NB];
  int tid = threadIdx.x;  // 256
  int e0 = blockIdx.x * CHUNK;
  int eend = min(e0 + CHUNK, E);
  hist[tid] = 0;
  __syncthreads();
  int dc[8], bc[8];                 // static-indexed caches (full unroll -> regs)
#pragma unroll
  for (int j = 0; j < 8; ++j) {
    int e = e0 + tid + j * 256;
    int d = -1;
    if (e < eend) {
      int dd = dstI[e];
      if ((unsigned)dd < (unsigned)N) d = dd;
    }
    int b = -1;
    if (d >= 0) {
      b = d / capN;
      atomicAdd(&hist[b], 1);
    }
    dc[j] = d; bc[j] = b;
  }
  __syncthreads();
  base[tid] = tid * capE + atomicAdd(&gcur[tid], hist[tid]);
  cnt[tid] = 0;
  __syncthreads();
#pragma unroll
  for (int j = 0; j < 8; ++j) {
    if (dc[j] >= 0) {
      int e = e0 + tid + j * 256;
      int s = srcI[e];
      if ((unsigned)s < (unsigned)N) {
        int b = bc[j];
        int slot = base[b] + atomicAdd(&cnt[b], 1);
        if (slot < (b + 1) * capE)
          pairs[slot] = ((dc[j] - b * capN) << 17) | s;
      }
    }
  }
}

// ---------------- phase 2: per-bucket CSR build ----------------
__launch_bounds__(512)
__global__ void k_csr(const int* __restrict__ pairs, const int* __restrict__ gcur,
                      int* __restrict__ deg, int* __restrict__ rowoff,
                      int* __restrict__ csr, int N, int capN, int capE) {
  __shared__ int hist[512];
  __shared__ int tmp[512];
  __shared__ int cur[512];
  int q = blockIdx.x;
  int tid = threadIdx.x;
  int nloc = N - q * capN;
  if (nloc > capN) nloc = capN;
  int base = q * capE;
  int cnt = gcur[q];
  if (cnt > capE) cnt = capE;
  int qbase = q * capN;
  hist[tid] = 0;
  __syncthreads();
  for (int e = tid; e < cnt; e += 512) {
    int code = pairs[base + e];
    int dl = (unsigned)code >> 17;
    if (dl < nloc) atomicAdd(&hist[dl], 1);
  }
  __syncthreads();
  int v = hist[tid];
  tmp[tid] = v;
  __syncthreads();
  for (int off = 1; off < 512; off <<= 1) {
    int t = (tid >= off) ? tmp[tid - off] : 0;
    __syncthreads();
    tmp[tid] += t;
    __syncthreads();
  }
  int ex = tmp[tid] - v;
  cur[tid] = ex;
  if (tid < nloc) {
    int i = qbase + tid;
    deg[i] = v;
    rowoff[i] = base + ex;
  }
  __syncthreads();
  for (int e = tid; e < cnt; e += 512) {
    int code = pairs[base + e];
    int dl = (unsigned)code >> 17;
    if (dl < nloc) {
      int pos = atomicAdd(&cur[dl], 1);
      csr[base + pos] = code & 0x1FFFF;
    }
  }
}

// ---------------- mean aggregate 64-dim, wide gather ------------------------------
// wave per node; lane = (g=lane>>4: edge slot 0..3, c=lane&15: dim quad).
// One 8B load covers dims 4c..4c+3 of edge-slot g -> 4 rows per wave-instruction.
__global__ void k_agg64(const __half* __restrict__ xh, const int* __restrict__ csr,
                        const int* __restrict__ rowoff, const int* __restrict__ deg,
                        float* __restrict__ m, int n) {
  int w = (blockIdx.x * blockDim.x + threadIdx.x) >> 6;
  int lane = threadIdx.x & 63;
  if (w >= n) return;
  int start = __builtin_amdgcn_readfirstlane(rowoff[w]);
  int d = __builtin_amdgcn_readfirstlane(deg[w]);
  int g = lane >> 4, c = lane & 15;
  int end = start + d;
  float a0 = 0.f, a1 = 0.f, a2 = 0.f, a3 = 0.f;
  for (int eb = start; eb < end; eb += 32) {
#pragma unroll
    for (int j = 0; j < 8; ++j) {
      int e = eb + j * 4 + g;
      if (e < end) {
        int s = csr[e];
        uint2 u = *(const uint2*)(xh + (size_t)s * 64 + c * 4);
        __half2 h0 = *(__half2*)&u.x;
        __half2 h1 = *(__half2*)&u.y;
        float2 f0 = __half22float2(h0);
        float2 f1 = __half22float2(h1);
        a0 += f0.x; a1 += f0.y; a2 += f1.x; a3 += f1.y;
      }
    }
  }
  // fold the 4 edge slots (lanes c, c+16, c+32, c+48)
  a0 += __shfl_xor(a0, 16); a1 += __shfl_xor(a1, 16);
  a2 += __shfl_xor(a2, 16); a3 += __shfl_xor(a3, 16);
  a0 += __shfl_xor(a0, 32); a1 += __shfl_xor(a1, 32);
  a2 += __shfl_xor(a2, 32); a3 += __shfl_xor(a3, 32);
  if (lane < 16) {
    float inv = (d > 0) ? 1.f / (float)d : 0.f;
    *(float4*)(m + (size_t)w * 64 + c * 4) =
        make_float4(a0 * inv, a1 * inv, a2 * inv, a3 * inv);
  }
}

// ---------------- layer1 GEMM: h = relu([m|x] @ [W1l;W1r] + b1) -------------------
__launch_bounds__(256, 4)
__global__ void k_h(const float* __restrict__ m, const float* __restrict__ x,
                    const float* __restrict__ Wl, const float* __restrict__ Wr,
                    const float* __restrict__ b1, float* __restrict__ h, int n) {
  __shared__ float sAT[32 * 68];
  __shared__ float sW[32 * 64];
  int tid = threadIdx.x;
  int row0 = blockIdx.x * 64;
  int colT = tid & 15;
  int rowT = tid >> 4;
  float acc[4][4];
#pragma unroll
  for (int r = 0; r < 4; ++r)
#pragma unroll
    for (int c = 0; c < 4; ++c) acc[r][c] = 0.f;

  for (int kt = 0; kt < 4; ++kt) {
    const float* asrc = (kt < 2) ? m : x;
    const float* wsrc = (kt < 2) ? Wl : Wr;
    int ko = (kt & 1) * 32;
    __syncthreads();
    {
      int f = tid;
#pragma unroll
      for (int i = 0; i < 2; ++i, f += 256) {
        int r = f >> 3, kq = f & 7;
        int rr = row0 + r; if (rr > n - 1) rr = n - 1;
        float4 v = *(const float4*)(asrc + (size_t)rr * 64 + ko + kq * 4);
        sAT[(kq * 4 + 0) * 68 + r] = v.x;
        sAT[(kq * 4 + 1) * 68 + r] = v.y;
        sAT[(kq * 4 + 2) * 68 + r] = v.z;
        sAT[(kq * 4 + 3) * 68 + r] = v.w;
      }
      int g = tid;
#pragma unroll
      for (int i = 0; i < 2; ++i, g += 256) {
        int wr = g >> 4, cq = g & 15;
        float4 v = *(const float4*)(wsrc + (size_t)(ko + wr) * 64 + cq * 4);
        *(float4*)&sW[wr * 64 + cq * 4] = v;
      }
    }
    __syncthreads();
#pragma unroll 4
    for (int k = 0; k < 32; ++k) {
      float4 a = *(const float4*)&sAT[k * 68 + rowT * 4];
      float4 w = *(const float4*)&sW[k * 64 + colT * 4];
      acc[0][0] += a.x * w.x; acc[0][1] += a.x * w.y; acc[0][2] += a.x * w.z; acc[0][3] += a.x * w.w;
      acc[1][0] += a.y * w.x; acc[1][1] += a.y * w.y; acc[1][2] += a.y * w.z; acc[1][3] += a.y * w.w;
      acc[2][0] += a.z * w.x; acc[2][1] += a.z * w.y; acc[2][2] += a.z * w.z; acc[2][3] += a.z * w.w;
      acc[3][0] += a.w * w.x; acc[3][1] += a.w * w.y; acc[3][2] += a.w * w.z; acc[3][3] += a.w * w.w;
    }
  }
  float4 bb = *(const float4*)(b1 + colT * 4);
#pragma unroll
  for (int r = 0; r < 4; ++r) {
    int row = row0 + rowT * 4 + r;
    if (row < n) {
      float4 o;
      o.x = fmaxf(acc[r][0] + bb.x, 0.f);
      o.y = fmaxf(acc[r][1] + bb.y, 0.f);
      o.z = fmaxf(acc[r][2] + bb.z, 0.f);
      o.w = fmaxf(acc[r][3] + bb.w, 0.f);
      *(float4*)(h + (size_t)row * 64 + colT * 4) = o;
    }
  }
}

// ---------------- layer2 GEMM: p16 = half(h@W2l), q = h@W2r (to d_out) ------------
__launch_bounds__(256, 4)
__global__ void k_pq(const float* __restrict__ h, const float* __restrict__ W2l,
                     const float* __restrict__ W2r, __half* __restrict__ p16,
                     float* __restrict__ q, int n) {
  __shared__ float sAT[32 * 132];
  __shared__ float sW[32 * 32];
  int tid = threadIdx.x;
  int row0 = blockIdx.x * 128;
  int colT = tid & 7;
  int rowT = tid >> 3;
  float acc[4][4];
#pragma unroll
  for (int r = 0; r < 4; ++r)
#pragma unroll
    for (int c = 0; c < 4; ++c) acc[r][c] = 0.f;

  for (int kt = 0; kt < 2; ++kt) {
    int ko = kt * 32;
    __syncthreads();
    {
      int f = tid;
#pragma unroll
      for (int i = 0; i < 4; ++i, f += 256) {
        int r = f >> 3, kq = f & 7;
        int rr = row0 + r; if (rr > n - 1) rr = n - 1;
        float4 v = *(const float4*)(h + (size_t)rr * 64 + ko + kq * 4);
        sAT[(kq * 4 + 0) * 132 + r] = v.x;
        sAT[(kq * 4 + 1) * 132 + r] = v.y;
        sAT[(kq * 4 + 2) * 132 + r] = v.z;
        sAT[(kq * 4 + 3) * 132 + r] = v.w;
      }
      int wr = tid >> 3, cq = tid & 7;
      const float* wsrc = (cq < 4) ? W2l : W2r;
      int cc = (cq & 3) * 4;
      float4 v = *(const float4*)(wsrc + (size_t)(ko + wr) * 16 + cc);
      *(float4*)&sW[wr * 32 + cq * 4] = v;
    }
    __syncthreads();
#pragma unroll 4
    for (int k = 0; k < 32; ++k) {
      float4 a = *(const float4*)&sAT[k * 132 + rowT * 4];
      float4 w = *(const float4*)&sW[k * 32 + colT * 4];
      acc[0][0] += a.x * w.x; acc[0][1] += a.x * w.y; acc[0][2] += a.x * w.z; acc[0][3] += a.x * w.w;
      acc[1][0] += a.y * w.x; acc[1][1] += a.y * w.y; acc[1][2] += a.y * w.z; acc[1][3] += a.y * w.w;
      acc[2][0] += a.z * w.x; acc[2][1] += a.z * w.y; acc[2][2] += a.z * w.z; acc[2][3] += a.z * w.w;
      acc[3][0] += a.w * w.x; acc[3][1] += a.w * w.y; acc[3][2] += a.w * w.z; acc[3][3] += a.w * w.w;
    }
  }
#pragma unroll
  for (int r = 0; r < 4; ++r) {
    int row = row0 + rowT * 4 + r;
    if (row < n) {
      if (colT < 4) {
        __half2* dst = (__half2*)(p16 + (size_t)row * 16 + colT * 4);
        dst[0] = __floats2half2_rn(acc[r][0], acc[r][1]);
        dst[1] = __floats2half2_rn(acc[r][2], acc[r][3]);
      } else {
        *(float4*)(q + (size_t)row * 16 + (colT - 4) * 4) =
            make_float4(acc[r][0], acc[r][1], acc[r][2], acc[r][3]);
      }
    }
  }
}

// ---------------- mean aggregate 16-dim, wide gather + epilogue -------------------
// wave per node; lane = (g=lane>>2: edge slot 0..15, c=lane&3: dim quad).
__global__ void k_agg16(const __half* __restrict__ p16, const int* __restrict__ csr,
                        const int* __restrict__ rowoff, const int* __restrict__ deg,
                        const float* __restrict__ b2, float* __restrict__ out, int n) {
  int i = (blockIdx.x * blockDim.x + threadIdx.x) >> 6;
  int lane = threadIdx.x & 63;
  if (i >= n) return;
  int start = __builtin_amdgcn_readfirstlane(rowoff[i]);
  int d = __builtin_amdgcn_readfirstlane(deg[i]);
  int g = lane >> 2, c = lane & 3;
  int end = start + d;
  float a0 = 0.f, a1 = 0.f, a2 = 0.f, a3 = 0.f;
  for (int eb = start; eb < end; eb += 32) {
#pragma unroll
    for (int j = 0; j < 2; ++j) {
      int e = eb + j * 16 + g;
      if (e < end) {
        int s = csr[e];
        uint2 u = *(const uint2*)(p16 + (size_t)s * 16 + c * 4);
        __half2 h0 = *(__half2*)&u.x;
        __half2 h1 = *(__half2*)&u.y;
        float2 f0 = __half22float2(h0);
        float2 f1 = __half22float2(h1);
        a0 += f0.x; a1 += f0.y; a2 += f1.x; a3 += f1.y;
      }
    }
  }
  // fold 16 edge slots: lanes c, c+4, c+8, ..., c+60
  a0 += __shfl_xor(a0, 4);  a1 += __shfl_xor(a1, 4);
  a2 += __shfl_xor(a2, 4);  a3 += __shfl_xor(a3, 4);
  a0 += __shfl_xor(a0, 8);  a1 += __shfl_xor(a1, 8);
  a2 += __shfl_xor(a2, 8);  a3 += __shfl_xor(a3, 8);
  a0 += __shfl_xor(a0, 16); a1 += __shfl_xor(a1, 16);
  a2 += __shfl_xor(a2, 16); a3 += __shfl_xor(a3, 16);
  a0 += __shfl_xor(a0, 32); a1 += __shfl_xor(a1, 32);
  a2 += __shfl_xor(a2, 32); a3 += __shfl_xor(a3, 32);
  if (lane < 4) {
    float inv = (d > 0) ? 1.f / (float)d : 0.f;
    size_t o = (size_t)i * 16 + c * 4;
    float4 qv = *(const float4*)(out + o);       // holds q = h@W2_r
    float4 bb = *(const float4*)(b2 + c * 4);
    *(float4*)(out + o) = make_float4(a0 * inv + qv.x + bb.x,
                                      a1 * inv + qv.y + bb.y,
                                      a2 * inv + qv.z + bb.z,
                                      a3 * inv + qv.w + bb.w);
  }
}

extern "C" void kernel_launch(void* const* d_in, const int* in_sizes, int n_in,
                              void* d_out, int out_size, void* d_ws, size_t ws_size,
                              hipStream_t stream) {
  const float* x   = (const float*)d_in[0];
  const int*   ei  = (const int*)d_in[1];
  const float* W1l = (const float*)d_in[2];
  const float* W1r = (const float*)d_in[3];
  const float* b1  = (const float*)d_in[4];
  const float* W2l = (const float*)d_in[5];
  const float* W2r = (const float*)d_in[6];
  const float* b2  = (const float*)d_in[7];
  float* out = (float*)d_out;

  int N = in_sizes[0] / 64;
  int E = in_sizes[1] / 2;
  const int* srcI = ei;
  const int* dstI = ei + E;

  int capN = (N + NB - 1) / NB;       // 391 (<512: fits 9-bit dl)
  int capE = E / NB + 1024;

  size_t off = 0;
  auto alloc = [&](size_t bytes) -> char* {
    char* r = (char*)d_ws + off;
    off = (off + bytes + 255) & ~(size_t)255;
    return r;
  };
  int*    deg    = (int*)alloc((size_t)N * 4);
  int*    rowoff = (int*)alloc((size_t)N * 4);
  int*    csr    = (int*)alloc((size_t)NB * capE * 4);
  int*    gcur   = (int*)alloc(NB * 4);
  __half* xh     = (__half*)alloc((size_t)N * 64 * 2);
  float*  m      = (float*)alloc((size_t)N * 64 * 4);
  float*  h      = (float*)alloc((size_t)N * 64 * 4);
  __half* p16    = (__half*)alloc((size_t)N * 16 * 2);
  int*    pairs  = (int*)h;           // overlay: pairs dead before h is written
  if (off > ws_size) return;          // visible failure if ws too small
  if ((size_t)NB * capE * 4 > (size_t)N * 64 * 4) return;
  if (N > (1 << 17) || capN > (1 << 9)) return;  // packing validity

  hipMemsetAsync(gcur, 0, NB * 4, stream);
  k_cvt<<<(N * 64 + 2047) / 2048, 256, 0, stream>>>(x, xh, N * 64);
  k_part<<<(E + CHUNK - 1) / CHUNK, 256, 0, stream>>>(srcI, dstI, gcur, pairs, E, N, capN, capE);
  k_csr<<<NB, 512, 0, stream>>>(pairs, gcur, deg, rowoff, csr, N, capN, capE);

  // layer 1: m = mean_agg(xh); h = relu(m@W1l + x@W1r + b1)
  k_agg64<<<(N * 64 + 255) / 256, 256, 0, stream>>>(xh, csr, rowoff, deg, m, N);
  k_h<<<(N + 63) / 64, 256, 0, stream>>>(m, x, W1l, W1r, b1, h, N);

  // layer 2 (transform-first): p16 = h@W2l (fp16), q = h@W2r (to d_out)
  k_pq<<<(N + 127) / 128, 256, 0, stream>>>(h, W2l, W2r, p16, out, N);
  k_agg16<<<(N * 64 + 255) / 256, 256, 0, stream>>>(p16, csr, rowoff, deg, b2, out, N);
}

// Round 11
// 226.969 us; speedup vs baseline: 3.7699x; 1.1523x over previous
//
#include <hip/hip_runtime.h>
#include <hip/hip_fp16.h>

#define NB 256      // dst-range buckets
#define CHUNK 2048  // edges per partition block
// pack: code = (dl<<17)|src ; valid because N=100000<2^17 and capN=391<2^9

// ---------------- phase 1: fused x->fp16 convert + edge partition -----------------
__launch_bounds__(256)
__global__ void k_partcvt(const int* __restrict__ srcI, const int* __restrict__ dstI,
                          const float* __restrict__ x, __half* __restrict__ xh, int total,
                          int* __restrict__ gcur, int* __restrict__ pairs,
                          int E, int N, int capN, int capE) {
  __shared__ int hist[NB];
  __shared__ int base[NB];
  __shared__ int cnt[NB];
  int tid = threadIdx.x;  // 256

  // fused convert: grid-stride, 8 floats per thread-iter (coalesced float4 x2)
  int gsz = gridDim.x * 256;
  for (int i = blockIdx.x * 256 + tid; i * 8 < total; i += gsz) {
    int i8 = i * 8;
    float4 a = *(const float4*)(x + i8);
    float4 b = *(const float4*)(x + i8 + 4);
    __half2* dst = (__half2*)(xh + i8);
    dst[0] = __floats2half2_rn(a.x, a.y);
    dst[1] = __floats2half2_rn(a.z, a.w);
    dst[2] = __floats2half2_rn(b.x, b.y);
    dst[3] = __floats2half2_rn(b.z, b.w);
  }

  int e0 = blockIdx.x * CHUNK;
  int eend = min(e0 + CHUNK, E);
  hist[tid] = 0;
  __syncthreads();
  int dc[8], bc[8];                 // static-indexed caches (full unroll -> regs)
#pragma unroll
  for (int j = 0; j < 8; ++j) {
    int e = e0 + tid + j * 256;
    int d = -1;
    if (e < eend) {
      int dd = dstI[e];
      if ((unsigned)dd < (unsigned)N) d = dd;
    }
    int b = -1;
    if (d >= 0) {
      b = d / capN;
      atomicAdd(&hist[b], 1);
    }
    dc[j] = d; bc[j] = b;
  }
  __syncthreads();
  base[tid] = tid * capE + atomicAdd(&gcur[tid], hist[tid]);
  cnt[tid] = 0;
  __syncthreads();
#pragma unroll
  for (int j = 0; j < 8; ++j) {
    if (dc[j] >= 0) {
      int e = e0 + tid + j * 256;
      int s = srcI[e];
      if ((unsigned)s < (unsigned)N) {
        int b = bc[j];
        int slot = base[b] + atomicAdd(&cnt[b], 1);
        if (slot < (b + 1) * capE)
          pairs[slot] = ((dc[j] - b * capN) << 17) | s;
      }
    }
  }
}

// ---------------- phase 2: per-bucket CSR build ----------------
__launch_bounds__(512)
__global__ void k_csr(const int* __restrict__ pairs, const int* __restrict__ gcur,
                      int* __restrict__ deg, int* __restrict__ rowoff,
                      int* __restrict__ csr, int N, int capN, int capE) {
  __shared__ int hist[512];
  __shared__ int tmp[512];
  __shared__ int cur[512];
  int q = blockIdx.x;
  int tid = threadIdx.x;
  int nloc = N - q * capN;
  if (nloc > capN) nloc = capN;
  int base = q * capE;
  int cnt = gcur[q];
  if (cnt > capE) cnt = capE;
  int qbase = q * capN;
  hist[tid] = 0;
  __syncthreads();
  for (int e = tid; e < cnt; e += 512) {
    int code = pairs[base + e];
    int dl = (unsigned)code >> 17;
    if (dl < nloc) atomicAdd(&hist[dl], 1);
  }
  __syncthreads();
  int v = hist[tid];
  tmp[tid] = v;
  __syncthreads();
  for (int off = 1; off < 512; off <<= 1) {
    int t = (tid >= off) ? tmp[tid - off] : 0;
    __syncthreads();
    tmp[tid] += t;
    __syncthreads();
  }
  int ex = tmp[tid] - v;
  cur[tid] = ex;
  if (tid < nloc) {
    int i = qbase + tid;
    deg[i] = v;
    rowoff[i] = base + ex;
  }
  __syncthreads();
  for (int e = tid; e < cnt; e += 512) {
    int code = pairs[base + e];
    int dl = (unsigned)code >> 17;
    if (dl < nloc) {
      int pos = atomicAdd(&cur[dl], 1);
      csr[base + pos] = code & 0x1FFFF;
    }
  }
}

// ---------------- mean aggregate 64-dim from fp16 (r8 form): wave/node, lane/dim --
__global__ void k_agg64(const __half* __restrict__ xh, const int* __restrict__ csr,
                        const int* __restrict__ rowoff, const int* __restrict__ deg,
                        float* __restrict__ m, int n) {
  int w = (blockIdx.x * blockDim.x + threadIdx.x) >> 6;
  int lane = threadIdx.x & 63;
  if (w >= n) return;
  int start = __builtin_amdgcn_readfirstlane(rowoff[w]);
  int d = __builtin_amdgcn_readfirstlane(deg[w]);
  float a0 = 0.f, a1 = 0.f, a2 = 0.f, a3 = 0.f;
  float a4 = 0.f, a5 = 0.f, a6 = 0.f, a7 = 0.f;
  int j = 0;
  for (; j + 7 < d; j += 8) {
    int s0 = csr[start + j], s1 = csr[start + j + 1];
    int s2 = csr[start + j + 2], s3 = csr[start + j + 3];
    int s4 = csr[start + j + 4], s5 = csr[start + j + 5];
    int s6 = csr[start + j + 6], s7 = csr[start + j + 7];
    a0 += __half2float(xh[(size_t)s0 * 64 + lane]);
    a1 += __half2float(xh[(size_t)s1 * 64 + lane]);
    a2 += __half2float(xh[(size_t)s2 * 64 + lane]);
    a3 += __half2float(xh[(size_t)s3 * 64 + lane]);
    a4 += __half2float(xh[(size_t)s4 * 64 + lane]);
    a5 += __half2float(xh[(size_t)s5 * 64 + lane]);
    a6 += __half2float(xh[(size_t)s6 * 64 + lane]);
    a7 += __half2float(xh[(size_t)s7 * 64 + lane]);
  }
  for (; j + 3 < d; j += 4) {
    int s0 = csr[start + j], s1 = csr[start + j + 1];
    int s2 = csr[start + j + 2], s3 = csr[start + j + 3];
    a0 += __half2float(xh[(size_t)s0 * 64 + lane]);
    a1 += __half2float(xh[(size_t)s1 * 64 + lane]);
    a2 += __half2float(xh[(size_t)s2 * 64 + lane]);
    a3 += __half2float(xh[(size_t)s3 * 64 + lane]);
  }
  for (; j < d; ++j) a0 += __half2float(xh[(size_t)csr[start + j] * 64 + lane]);
  float inv = (d > 0) ? 1.f / (float)d : 0.f;
  m[(size_t)w * 64 + lane] = (((a0 + a1) + (a2 + a3)) + ((a4 + a5) + (a6 + a7))) * inv;
}

// ---------------- fused layer1+layer2 GEMM per 64-row tile ------------------------
// Phase A: h = relu([m|x] @ [W1l;W1r] + b1) into LDS hT[64dim][68].
// Phase B: p16 = half(h@W2l), q = h@W2r from LDS. LDS phases overlaid (25.6 KB).
__launch_bounds__(256, 4)
__global__ void k_hpq(const float* __restrict__ m, const float* __restrict__ x,
                      const float* __restrict__ W1l, const float* __restrict__ W1r,
                      const float* __restrict__ b1, const float* __restrict__ W2l,
                      const float* __restrict__ W2r, __half* __restrict__ p16,
                      float* __restrict__ q, int n) {
  __shared__ float smem[6400];    // 25.6 KB
  float* sAT = smem;              // phase A: [32k][68]  (2176)
  float* sW  = smem + 2176;       // phase A: [32k][64]  (2048)
  float* hT  = smem;              // phase B: [64dim][68] (4352) — overlays A
  float* sW2 = smem + 4352;       // phase B: [64k][32]  (2048) — disjoint from A
  int tid = threadIdx.x;
  int row0 = blockIdx.x * 64;
  int colT = tid & 15;
  int rowT = tid >> 4;

  // stage W2 early (region disjoint from phase A; no reader until after barrier 2)
  {
    int g = tid;
#pragma unroll
    for (int i = 0; i < 2; ++i, g += 256) {
      int wr = g >> 3, cq = g & 7;
      const float* wsrc = (cq < 4) ? W2l : W2r;
      int cc = (cq & 3) * 4;
      float4 v = *(const float4*)(wsrc + (size_t)wr * 16 + cc);
      *(float4*)&sW2[wr * 32 + cq * 4] = v;
    }
  }

  float acc[4][4];
#pragma unroll
  for (int r = 0; r < 4; ++r)
#pragma unroll
    for (int c = 0; c < 4; ++c) acc[r][c] = 0.f;

  for (int kt = 0; kt < 4; ++kt) {
    const float* asrc = (kt < 2) ? m : x;
    const float* wsrc = (kt < 2) ? W1l : W1r;
    int ko = (kt & 1) * 32;
    __syncthreads();
    {
      int f = tid;
#pragma unroll
      for (int i = 0; i < 2; ++i, f += 256) {
        int r = f >> 3, kq = f & 7;
        int rr = row0 + r; if (rr > n - 1) rr = n - 1;
        float4 v = *(const float4*)(asrc + (size_t)rr * 64 + ko + kq * 4);
        sAT[(kq * 4 + 0) * 68 + r] = v.x;
        sAT[(kq * 4 + 1) * 68 + r] = v.y;
        sAT[(kq * 4 + 2) * 68 + r] = v.z;
        sAT[(kq * 4 + 3) * 68 + r] = v.w;
      }
      int g = tid;
#pragma unroll
      for (int i = 0; i < 2; ++i, g += 256) {
        int wr = g >> 4, cq = g & 15;
        float4 v = *(const float4*)(wsrc + (size_t)(ko + wr) * 64 + cq * 4);
        *(float4*)&sW[wr * 64 + cq * 4] = v;
      }
    }
    __syncthreads();
#pragma unroll 4
    for (int k = 0; k < 32; ++k) {
      float4 a = *(const float4*)&sAT[k * 68 + rowT * 4];
      float4 w = *(const float4*)&sW[k * 64 + colT * 4];
      acc[0][0] += a.x * w.x; acc[0][1] += a.x * w.y; acc[0][2] += a.x * w.z; acc[0][3] += a.x * w.w;
      acc[1][0] += a.y * w.x; acc[1][1] += a.y * w.y; acc[1][2] += a.y * w.z; acc[1][3] += a.y * w.w;
      acc[2][0] += a.z * w.x; acc[2][1] += a.z * w.y; acc[2][2] += a.z * w.z; acc[2][3] += a.z * w.w;
      acc[3][0] += a.w * w.x; acc[3][1] += a.w * w.y; acc[3][2] += a.w * w.z; acc[3][3] += a.w * w.w;
    }
  }
  __syncthreads();   // phase-A LDS reads complete before hT overlays sAT/sW

  // bias + relu; write h-tile transposed [dim][row]
  {
    float4 bb = *(const float4*)(b1 + colT * 4);
    float bbv[4] = {bb.x, bb.y, bb.z, bb.w};
#pragma unroll
    for (int c = 0; c < 4; ++c) {
      float4 hv;
      hv.x = fmaxf(acc[0][c] + bbv[c], 0.f);
      hv.y = fmaxf(acc[1][c] + bbv[c], 0.f);
      hv.z = fmaxf(acc[2][c] + bbv[c], 0.f);
      hv.w = fmaxf(acc[3][c] + bbv[c], 0.f);
      *(float4*)&hT[(colT * 4 + c) * 68 + rowT * 4] = hv;
    }
  }
  __syncthreads();

  // phase B: [64 rows]x[32 cols] from hT/sW2; 256 thr = 8 colT2 x 32 rowT2, micro 2x4
  int colT2 = tid & 7;
  int rowT2 = tid >> 3;
  float acc2[2][4];
#pragma unroll
  for (int r = 0; r < 2; ++r)
#pragma unroll
    for (int c = 0; c < 4; ++c) acc2[r][c] = 0.f;
#pragma unroll 4
  for (int k = 0; k < 64; ++k) {
    float2 a = *(const float2*)&hT[k * 68 + rowT2 * 2];
    float4 w = *(const float4*)&sW2[k * 32 + colT2 * 4];
    acc2[0][0] += a.x * w.x; acc2[0][1] += a.x * w.y; acc2[0][2] += a.x * w.z; acc2[0][3] += a.x * w.w;
    acc2[1][0] += a.y * w.x; acc2[1][1] += a.y * w.y; acc2[1][2] += a.y * w.z; acc2[1][3] += a.y * w.w;
  }
#pragma unroll
  for (int r = 0; r < 2; ++r) {
    int row = row0 + rowT2 * 2 + r;
    if (row < n) {
      if (colT2 < 4) {
        __half2* dst = (__half2*)(p16 + (size_t)row * 16 + colT2 * 4);
        dst[0] = __floats2half2_rn(acc2[r][0], acc2[r][1]);
        dst[1] = __floats2half2_rn(acc2[r][2], acc2[r][3]);
      } else {
        *(float4*)(q + (size_t)row * 16 + (colT2 - 4) * 4) =
            make_float4(acc2[r][0], acc2[r][1], acc2[r][2], acc2[r][3]);
      }
    }
  }
}

// ---------------- mean aggregate 16-dim (fp16, r8 form) + epilogue ----------------
__global__ void k_agg16(const __half* __restrict__ p16, const int* __restrict__ csr,
                        const int* __restrict__ rowoff, const int* __restrict__ deg,
                        const float* __restrict__ b2, float* __restrict__ out, int n) {
  int t = blockIdx.x * blockDim.x + threadIdx.x;
  int i = t >> 4;
  int dd = t & 15;
  if (i >= n) return;
  int start = rowoff[i];
  int d = deg[i];
  float a0 = 0.f, a1 = 0.f, a2 = 0.f, a3 = 0.f;
  float a4 = 0.f, a5 = 0.f, a6 = 0.f, a7 = 0.f;
  int j = 0;
  for (; j + 7 < d; j += 8) {
    int s0 = csr[start + j], s1 = csr[start + j + 1];
    int s2 = csr[start + j + 2], s3 = csr[start + j + 3];
    int s4 = csr[start + j + 4], s5 = csr[start + j + 5];
    int s6 = csr[start + j + 6], s7 = csr[start + j + 7];
    a0 += __half2float(p16[(size_t)s0 * 16 + dd]);
    a1 += __half2float(p16[(size_t)s1 * 16 + dd]);
    a2 += __half2float(p16[(size_t)s2 * 16 + dd]);
    a3 += __half2float(p16[(size_t)s3 * 16 + dd]);
    a4 += __half2float(p16[(size_t)s4 * 16 + dd]);
    a5 += __half2float(p16[(size_t)s5 * 16 + dd]);
    a6 += __half2float(p16[(size_t)s6 * 16 + dd]);
    a7 += __half2float(p16[(size_t)s7 * 16 + dd]);
  }
  for (; j + 3 < d; j += 4) {
    int s0 = csr[start + j], s1 = csr[start + j + 1];
    int s2 = csr[start + j + 2], s3 = csr[start + j + 3];
    a0 += __half2float(p16[(size_t)s0 * 16 + dd]);
    a1 += __half2float(p16[(size_t)s1 * 16 + dd]);
    a2 += __half2float(p16[(size_t)s2 * 16 + dd]);
    a3 += __half2float(p16[(size_t)s3 * 16 + dd]);
  }
  for (; j < d; ++j) a0 += __half2float(p16[(size_t)csr[start + j] * 16 + dd]);
  float inv = (d > 0) ? 1.f / (float)d : 0.f;
  out[t] = ((((a0 + a1) + (a2 + a3)) + ((a4 + a5) + (a6 + a7)))) * inv + out[t] + b2[dd];
}

extern "C" void kernel_launch(void* const* d_in, const int* in_sizes, int n_in,
                              void* d_out, int out_size, void* d_ws, size_t ws_size,
                              hipStream_t stream) {
  const float* x   = (const float*)d_in[0];
  const int*   ei  = (const int*)d_in[1];
  const float* W1l = (const float*)d_in[2];
  const float* W1r = (const float*)d_in[3];
  const float* b1  = (const float*)d_in[4];
  const float* W2l = (const float*)d_in[5];
  const float* W2r = (const float*)d_in[6];
  const float* b2  = (const float*)d_in[7];
  float* out = (float*)d_out;

  int N = in_sizes[0] / 64;
  int E = in_sizes[1] / 2;
  const int* srcI = ei;
  const int* dstI = ei + E;

  int capN = (N + NB - 1) / NB;       // 391 (<512: fits 9-bit dl)
  int capE = E / NB + 1024;

  size_t off = 0;
  auto alloc = [&](size_t bytes) -> char* {
    char* r = (char*)d_ws + off;
    off = (off + bytes + 255) & ~(size_t)255;
    return r;
  };
  int*    deg    = (int*)alloc((size_t)N * 4);
  int*    rowoff = (int*)alloc((size_t)N * 4);
  int*    csr    = (int*)alloc((size_t)NB * capE * 4);
  int*    gcur   = (int*)alloc(NB * 4);
  __half* xh     = (__half*)alloc((size_t)N * 64 * 2);
  float*  m      = (float*)alloc((size_t)N * 64 * 4);
  __half* p16    = (__half*)alloc((size_t)N * 16 * 2);
  int*    pairs  = (int*)m;           // overlay: pairs dead before m is written
  if (off > ws_size) return;          // visible failure if ws too small
  if ((size_t)NB * capE * 4 > (size_t)N * 64 * 4) return;
  if (N > (1 << 17) || capN > (1 << 9)) return;  // packing validity

  hipMemsetAsync(gcur, 0, NB * 4, stream);
  k_partcvt<<<(E + CHUNK - 1) / CHUNK, 256, 0, stream>>>(srcI, dstI, x, xh, N * 64,
                                                         gcur, pairs, E, N, capN, capE);
  k_csr<<<NB, 512, 0, stream>>>(pairs, gcur, deg, rowoff, csr, N, capN, capE);

  // layer 1: m = mean_agg(xh); fused layer1+2 GEMMs: p16, q(out)
  k_agg64<<<(N * 64 + 255) / 256, 256, 0, stream>>>(xh, csr, rowoff, deg, m, N);
  k_hpq<<<(N + 63) / 64, 256, 0, stream>>>(m, x, W1l, W1r, b1, W2l, W2r, p16, out, N);

  // epilogue: out = mean_agg(p16) + q + b2
  k_agg16<<<(N * 16 + 255) / 256, 256, 0, stream>>>(p16, csr, rowoff, deg, b2, out, N);
}